// Round 15
// baseline (68.865 us; speedup 1.0000x reference)
//
#include <hip/hip_runtime.h>
#include <stdint.h>

#define BATCH 8
#define SEQ   2048
#define DIM   256
#define NKV   64                 // kv tiles of 32 rows
#define KT8   8192               // fp8 K/V tile: 8 pair-frags x 1KB
#define NWT   16
#define WT    16384              // bf16 W tile: 16 frags x 1KB
#define VOFF  ((size_t)BATCH * NKV * KT8)          // 4 MiB
#define WOFF  (VOFF + (size_t)BATCH * NKV * KT8)   // 8 MiB
#define C1    0.090215498f       // (1/16) * log2(e)
#define THRRAW 88.6766f          // 8 / C1  (defer-max threshold in raw S units)

typedef __attribute__((ext_vector_type(8))) short bf16x8;
typedef __attribute__((ext_vector_type(4))) float f32x4;
typedef __attribute__((ext_vector_type(4))) unsigned int u32x4;
typedef __attribute__((ext_vector_type(2))) long long i64x2;   // MFMA-ready operand pair

__device__ __forceinline__ unsigned short f2bf(float x) {
    unsigned u = __float_as_uint(x);
    unsigned r = u + 0x7fffu + ((u >> 16) & 1u);     // RNE
    return (unsigned short)(r >> 16);
}
__device__ __forceinline__ unsigned pack2(float a, float b) {
    return (unsigned)f2bf(a) | ((unsigned)f2bf(b) << 16);
}
__device__ __forceinline__ float exp2_fast(float x) {
    float r;
    asm("v_exp_f32 %0, %1" : "=v"(r) : "v"(x));
    return r;
}
__device__ __forceinline__ unsigned pk8x4(float a, float b, float c, float d) {
    unsigned u = __builtin_amdgcn_cvt_pk_fp8_f32(a, b, 0, false);
    return __builtin_amdgcn_cvt_pk_fp8_f32(c, d, u, true);
}
__device__ __forceinline__ long long mk64(unsigned lo, unsigned hi) {
    return (long long)(((unsigned long long)hi << 32) | lo);
}
__device__ __forceinline__ unsigned bperm(int srclane, unsigned v) {
    return (unsigned)__builtin_amdgcn_ds_bpermute(srclane * 4, (int)v);
}

// K: fp8 swapped-A pair-frags; V: fp8 B pair-frags; W: bf16 frag-major (as R8/R9).
__global__ void prep_frags(const float* __restrict__ K, const float* __restrict__ V,
                           const float* __restrict__ W, uint8_t* __restrict__ ws) {
    const int bid = blockIdx.x, tid = threadIdx.x;
    const int lane = tid & 63, fb = tid >> 6, g = lane >> 4, nn = lane & 15;
    if (bid < BATCH * NKV) {
        const float* src = K + (size_t)bid * 32 * DIM;
        uint8_t* dst = ws + (size_t)bid * KT8;
#pragma unroll
        for (int p = 0; p < 2; ++p) {
            int pr = p * 4 + fb, t2 = pr >> 2, kk2 = pr & 3;
            const float* rp = src + (size_t)(t2 * 16 + nn) * DIM + kk2 * 64 + g * 8;
            float4 a  = *(const float4*)(rp);
            float4 a2 = *(const float4*)(rp + 4);
            float4 c  = *(const float4*)(rp + 32);
            float4 c2 = *(const float4*)(rp + 36);
            u32x4 u = {pk8x4(a.x, a.y, a.z, a.w), pk8x4(a2.x, a2.y, a2.z, a2.w),
                       pk8x4(c.x, c.y, c.z, c.w), pk8x4(c2.x, c2.y, c2.z, c2.w)};
            *(u32x4*)(dst + pr * 1024 + lane * 16) = u;
        }
    } else if (bid < 2 * BATCH * NKV) {
        const int id = bid - BATCH * NKV;
        const float* src = V + (size_t)id * 32 * DIM;
        uint8_t* dst = ws + VOFF + (size_t)id * KT8;
#pragma unroll
        for (int p = 0; p < 2; ++p) {
            int pr = p * 4 + fb;
            float v0[8], v1[8];
#pragma unroll
            for (int j = 0; j < 8; ++j) {
                v0[j] = src[(size_t)(g * 8 + j) * DIM + pr * 32 + nn];
                v1[j] = src[(size_t)(g * 8 + j) * DIM + pr * 32 + 16 + nn];
            }
            u32x4 u = {pk8x4(v0[0], v0[1], v0[2], v0[3]), pk8x4(v0[4], v0[5], v0[6], v0[7]),
                       pk8x4(v1[0], v1[1], v1[2], v1[3]), pk8x4(v1[4], v1[5], v1[6], v1[7])};
            *(u32x4*)(dst + pr * 1024 + lane * 16) = u;
        }
    } else {
        const int wt = bid - 2 * BATCH * NKV;
        const float* src = W + (size_t)wt * 32 * DIM;
        uint8_t* dst = ws + WOFF + (size_t)wt * WT;
#pragma unroll
        for (int p = 0; p < 4; ++p) {
            int d = p * 4 + fb;
            float v[8];
#pragma unroll
            for (int j = 0; j < 8; ++j)
                v[j] = src[(size_t)(g * 8 + j) * DIM + d * 16 + nn];
            u32x4 u = {pack2(v[0], v[1]), pack2(v[2], v[3]),
                       pack2(v[4], v[5]), pack2(v[6], v[7])};
            *(u32x4*)(dst + d * 1024 + lane * 16) = u;
        }
    }
}

// smem: cbuf f32[32][256] [0,32768) | cbn bf16[32][264] [32768,49664)
//       mws[4][32] [49664,50176) | lws [50176,50688) | lgb[32] [50688,50816)
#define SMEM_BYTES 50816

__launch_bounds__(256, 2)
__global__ void attn_main(const float* __restrict__ Q, const float* __restrict__ bias,
                          const uint8_t* __restrict__ ws, float* __restrict__ out) {
    __shared__ __align__(16) uint8_t smem[SMEM_BYTES];
    float* cbuf = (float*)smem;
    uint8_t* cbn = smem + 32768;
    float* mws = (float*)(smem + 49664);
    float* lws = (float*)(smem + 50176);
    float* lgb = (float*)(smem + 50688);

    const int tid = threadIdx.x;
    const int wid = tid >> 6, lane = tid & 63, g = lane >> 4, nn = lane & 15;
    const int b = blockIdx.x & 7, qg = blockIdx.x >> 3;   // batch -> XCD affinity
    const int q0 = qg * 32;

    {   // zero merge accumulator (ordered by the first __syncthreads)
        f32x4 z = {0.f, 0.f, 0.f, 0.f};
        float* p = cbuf + tid * 32;
#pragma unroll
        for (int i = 0; i < 8; ++i) *(f32x4*)(p + i * 4) = z;
    }

    // Q as fp8 B-frags for swapped QK, 2 q-subtiles (col=q=nn, k = t8*32 + g*8 + j)
    const float* qbase = Q + ((size_t)b * SEQ + q0 + nn) * DIM + g * 8;
    long long qp[2][8];
#pragma unroll
    for (int rt = 0; rt < 2; ++rt)
#pragma unroll
        for (int t8 = 0; t8 < 8; ++t8) {
            const float* rp = qbase + (size_t)rt * 16 * DIM + t8 * 32;
            float4 a = *(const float4*)(rp);
            float4 c = *(const float4*)(rp + 4);
            qp[rt][t8] = mk64(pk8x4(a.x, a.y, a.z, a.w), pk8x4(c.x, c.y, c.z, c.w));
        }

    f32x4 ctx[2][16];
#pragma unroll
    for (int rt = 0; rt < 2; ++rt)
#pragma unroll
        for (int d = 0; d < 16; ++d) ctx[rt][d] = (f32x4){0.f, 0.f, 0.f, 0.f};
    float m[2] = {-3e38f, -3e38f}, mc[2] = {0.f, 0.f}, l[2] = {0.f, 0.f};

    const uint8_t* kws = ws + ((size_t)b * NKV + wid * 16) * KT8 + lane * 16;
    const uint8_t* vws = ws + VOFF + ((size_t)b * NKV + wid * 16) * KT8 + lane * 16;

    // prologue: K(0) in flight before the loop
    i64x2 kp[8];
#pragma unroll
    for (int i = 0; i < 8; ++i) kp[i] = *(const i64x2*)(kws + i * 1024);

    for (int t = 0; t < 16; ++t) {
        const uint8_t* vf = vws + (size_t)t * KT8;
        const uint8_t* kfn = kws + (size_t)((t + 1 < 16) ? t + 1 : 15) * KT8;
        // V(t) issued at top: consumed in PV, covered by QK+softmax
        i64x2 vp[8];
#pragma unroll
        for (int i = 0; i < 8; ++i) vp[i] = *(const i64x2*)(vf + i * 1024);
        // ---- S^T = K Q for both q-subtiles (K frags shared) ----
        f32x4 s[2][2];
#pragma unroll
        for (int rt = 0; rt < 2; ++rt) { s[rt][0] = (f32x4){0.f,0.f,0.f,0.f}; s[rt][1] = s[rt][0]; }
        __builtin_amdgcn_s_setprio(1);
#pragma unroll
        for (int kk = 0; kk < 8; ++kk) {
            int i = kk >> 1, h = kk & 1;
            long long ka  = kp[i][h];
            long long kb2 = kp[4 + i][h];
#pragma unroll
            for (int rt = 0; rt < 2; ++rt) {
                s[rt][0] = __builtin_amdgcn_mfma_f32_16x16x32_fp8_fp8(ka,  qp[rt][kk], s[rt][0], 0, 0, 0);
                s[rt][1] = __builtin_amdgcn_mfma_f32_16x16x32_fp8_fp8(kb2, qp[rt][kk], s[rt][1], 0, 0, 0);
            }
        }
        __builtin_amdgcn_s_setprio(0);
        // K(t+1) into the SAME buffer (kp dead after QK): covered by softmax+PV+V(t+1)
#pragma unroll
        for (int i = 0; i < 8; ++i) kp[i] = *(const i64x2*)(kfn + i * 1024);
        // ---- defer-max online softmax (per-lane scalar state, q = nn) ----
        float smax[2];
        int need = 0;
#pragma unroll
        for (int rt = 0; rt < 2; ++rt) {
            smax[rt] = fmaxf(fmaxf(fmaxf(s[rt][0][0], s[rt][0][1]), fmaxf(s[rt][0][2], s[rt][0][3])),
                             fmaxf(fmaxf(s[rt][1][0], s[rt][1][1]), fmaxf(s[rt][1][2], s[rt][1][3])));
            need |= (smax[rt] > m[rt] + THRRAW);
        }
        if (__any(need)) {                          // ~only at t=0 (cold path)
#pragma unroll
            for (int rt = 0; rt < 2; ++rt) {
                float v = smax[rt];
                v = fmaxf(v, __shfl_xor(v, 16));
                v = fmaxf(v, __shfl_xor(v, 32));
                float mn = fmaxf(m[rt], v);
                float sc0 = exp2_fast((m[rt] - mn) * C1);
                m[rt] = mn; mc[rt] = mn * C1; l[rt] *= sc0;
                float scr[4];
#pragma unroll
                for (int r = 0; r < 4; ++r)
                    scr[r] = __uint_as_float(bperm(4 * g + r, __float_as_uint(sc0)));
#pragma unroll
                for (int d = 0; d < 16; ++d)
#pragma unroll
                    for (int r = 0; r < 4; ++r) ctx[rt][d][r] *= scr[r];
            }
        }
        long long A[2];
#pragma unroll
        for (int rt = 0; rt < 2; ++rt) {
            float p0[4], p1[4];
#pragma unroll
            for (int r = 0; r < 4; ++r) {
                p0[r] = exp2_fast(__builtin_fmaf(s[rt][0][r], C1, -mc[rt]));   // <= 2^8 < 448
                p1[r] = exp2_fast(__builtin_fmaf(s[rt][1][r], C1, -mc[rt]));
                l[rt] += p0[r] + p1[r];
            }
            // P redistribution to PV A-layout via 2 permlane swaps (VALU, no LDS):
            // swap32: a=[kv0-7|kv16-23], b=[kv8-15|kv24-31]; swap16: a=kv[8g..], b=kv[8g+4..]
            unsigned pa  = pk8x4(p0[0], p0[1], p0[2], p0[3]);
            unsigned pb2 = pk8x4(p1[0], p1[1], p1[2], p1[3]);
            asm("v_permlane32_swap_b32 %0, %1" : "+v"(pa), "+v"(pb2));
            asm("v_permlane16_swap_b32 %0, %1" : "+v"(pa), "+v"(pb2));
            A[rt] = mk64(pa, pb2);
        }
        // ---- ctx += P V (V frags shared across subtiles; operands direct from vp) ----
        __builtin_amdgcn_s_setprio(1);
#pragma unroll
        for (int i = 0; i < 8; ++i) {
            long long v0 = vp[i][0], v1 = vp[i][1];
#pragma unroll
            for (int rt = 0; rt < 2; ++rt) {
                ctx[rt][2 * i]     = __builtin_amdgcn_mfma_f32_16x16x32_fp8_fp8(A[rt], v0, ctx[rt][2 * i], 0, 0, 0);
                ctx[rt][2 * i + 1] = __builtin_amdgcn_mfma_f32_16x16x32_fp8_fp8(A[rt], v1, ctx[rt][2 * i + 1], 0, 0, 0);
            }
        }
        __builtin_amdgcn_s_setprio(0);
    }

    // reduce l across the 4 lane-groups holding the same q
#pragma unroll
    for (int rt = 0; rt < 2; ++rt) {
        l[rt] += __shfl_xor(l[rt], 16);
        l[rt] += __shfl_xor(l[rt], 32);
    }

    if (lane < 16) {
#pragma unroll
        for (int rt = 0; rt < 2; ++rt) {
            mws[wid * 32 + rt * 16 + nn] = m[rt];
            lws[wid * 32 + rt * 16 + nn] = l[rt];
        }
    }
    __syncthreads();
    float sc[2][4];
#pragma unroll
    for (int rt = 0; rt < 2; ++rt)
#pragma unroll
        for (int r = 0; r < 4; ++r) {
            int row = rt * 16 + g * 4 + r;
            float m0 = mws[row], m1 = mws[32 + row], m2 = mws[64 + row], m3 = mws[96 + row];
            float mg = fmaxf(fmaxf(m0, m1), fmaxf(m2, m3));
            float lg = lws[row]      * exp2_fast((m0 - mg) * C1)
                     + lws[32 + row] * exp2_fast((m1 - mg) * C1)
                     + lws[64 + row] * exp2_fast((m2 - mg) * C1)
                     + lws[96 + row] * exp2_fast((m3 - mg) * C1);
            sc[rt][r] = exp2_fast((mws[wid * 32 + row] - mg) * C1);
            if (wid == 0 && nn == 0) lgb[row] = lg;
        }
    for (int w = 0; w < 4; ++w) {               // deterministic sequential merge
        if (wid == w) {
#pragma unroll
            for (int rt = 0; rt < 2; ++rt)
#pragma unroll
                for (int d = 0; d < 16; ++d)
#pragma unroll
                    for (int r = 0; r < 4; ++r) {
                        float* p = cbuf + (size_t)(rt * 16 + g * 4 + r) * 256 + d * 16 + nn;
                        *p += ctx[rt][d][r] * sc[rt][r];
                    }
        }
        __syncthreads();
    }
    {   // normalize + bf16 image cbn[32][264]
        int row = tid >> 3, c0 = (tid & 7) * 32;
        float il = 1.0f / lgb[row];
        const float* src = cbuf + (size_t)row * 256 + c0;
        uint8_t* dp = cbn + (size_t)row * 528 + c0 * 2;
#pragma unroll
        for (int i = 0; i < 4; ++i) {
            f32x4 a = *(const f32x4*)(src + i * 8);
            f32x4 c = *(const f32x4*)(src + i * 8 + 4);
            u32x4 u = {pack2(a[0] * il, a[1] * il), pack2(a[2] * il, a[3] * il),
                       pack2(c[0] * il, c[1] * il), pack2(c[2] * il, c[3] * il)};
            *(u32x4*)(dp + i * 16) = u;
        }
    }
    __syncthreads();

    // ---- epilogue: out = [ctxn, Q] @ W + b (bf16; Q reloaded) ----
    bf16x8 qe[2][8];
#pragma unroll
    for (int rt = 0; rt < 2; ++rt)
#pragma unroll
        for (int t8 = 0; t8 < 8; ++t8) {
            const float* rp = qbase + (size_t)rt * 16 * DIM + t8 * 32;
            float4 a = *(const float4*)(rp);
            float4 c = *(const float4*)(rp + 4);
            union { bf16x8 v; unsigned u[4]; } tmp;
            tmp.u[0] = pack2(a.x, a.y); tmp.u[1] = pack2(a.z, a.w);
            tmp.u[2] = pack2(c.x, c.y); tmp.u[3] = pack2(c.z, c.w);
            qe[rt][t8] = tmp.v;
        }
    f32x4 oacc[2][4];
#pragma unroll
    for (int rt = 0; rt < 2; ++rt)
#pragma unroll
        for (int dd = 0; dd < 4; ++dd) oacc[rt][dd] = (f32x4){0.f, 0.f, 0.f, 0.f};
    const uint8_t* wws = ws + WOFF + lane * 16;
    for (int wt = 0; wt < NWT; ++wt) {
        bf16x8 af[2];
#pragma unroll
        for (int rt = 0; rt < 2; ++rt) {
            if (wt < 8) af[rt] = *(const bf16x8*)(cbn + (size_t)(rt * 16 + nn) * 528 + wt * 64 + g * 16);
            else        af[rt] = qe[rt][wt - 8];
        }
#pragma unroll
        for (int dd = 0; dd < 4; ++dd) {
            bf16x8 wf = *(const bf16x8*)(wws + (size_t)(wt * 16 + wid * 4 + dd) * 1024);
#pragma unroll
            for (int rt = 0; rt < 2; ++rt)
                oacc[rt][dd] = __builtin_amdgcn_mfma_f32_16x16x32_bf16(af[rt], wf, oacc[rt][dd], 0, 0, 0);
        }
    }
#pragma unroll
    for (int rt = 0; rt < 2; ++rt) {
        float* obase = out + ((size_t)b * SEQ + q0 + rt * 16) * DIM + wid * 64;
#pragma unroll
        for (int dd = 0; dd < 4; ++dd) {
            float bv = bias[wid * 64 + dd * 16 + nn];
#pragma unroll
            for (int r = 0; r < 4; ++r)
                obase[(size_t)(g * 4 + r) * DIM + dd * 16 + nn] = oacc[rt][dd][r] + bv;
        }
    }
}

extern "C" void kernel_launch(void* const* d_in, const int* in_sizes, int n_in,
                              void* d_out, int out_size, void* d_ws, size_t ws_size,
                              hipStream_t stream) {
    const float* Q    = (const float*)d_in[0];
    const float* K    = (const float*)d_in[1];
    const float* V    = (const float*)d_in[2];
    const float* W    = (const float*)d_in[3];
    const float* bias = (const float*)d_in[4];
    float* out = (float*)d_out;
    uint8_t* ws = (uint8_t*)d_ws;
    prep_frags<<<2 * BATCH * NKV + NWT, 256, 0, stream>>>(K, V, W, ws);
    attn_main<<<BATCH * SEQ / 32, 256, 0, stream>>>(Q, bias, ws, out);
}

// Round 16
// 60.410 us; speedup vs baseline: 1.1400x; 1.1400x over previous
//
#include <hip/hip_runtime.h>
#include <stdint.h>

#define BATCH 8
#define SEQ   2048
#define DIM   256
#define NKV   64                 // kv tiles of 32 rows
#define KT8   8192               // fp8 K/V tile: 8 pair-frags x 1KB
#define NWT   16
#define WT    16384              // bf16 W tile: 16 frags x 1KB
#define VOFF  ((size_t)BATCH * NKV * KT8)          // 4 MiB
#define WOFF  (VOFF + (size_t)BATCH * NKV * KT8)   // 8 MiB
#define C1    0.090215498f       // (1/16) * log2(e)
#define THRRAW 88.6766f          // 8 / C1  (defer-max threshold in raw S units)

typedef __attribute__((ext_vector_type(8))) short bf16x8;
typedef __attribute__((ext_vector_type(4))) float f32x4;
typedef __attribute__((ext_vector_type(4))) unsigned int u32x4;
typedef __attribute__((ext_vector_type(2))) long long i64x2;   // MFMA-ready operand pair

__device__ __forceinline__ unsigned short f2bf(float x) {
    unsigned u = __float_as_uint(x);
    unsigned r = u + 0x7fffu + ((u >> 16) & 1u);     // RNE
    return (unsigned short)(r >> 16);
}
__device__ __forceinline__ unsigned pack2(float a, float b) {
    return (unsigned)f2bf(a) | ((unsigned)f2bf(b) << 16);
}
__device__ __forceinline__ float exp2_fast(float x) {
    float r;
    asm("v_exp_f32 %0, %1" : "=v"(r) : "v"(x));
    return r;
}
__device__ __forceinline__ unsigned pk8x4(float a, float b, float c, float d) {
    unsigned u = __builtin_amdgcn_cvt_pk_fp8_f32(a, b, 0, false);
    return __builtin_amdgcn_cvt_pk_fp8_f32(c, d, u, true);
}
__device__ __forceinline__ long long mk64(unsigned lo, unsigned hi) {
    return (long long)(((unsigned long long)hi << 32) | lo);
}
__device__ __forceinline__ unsigned bperm(int srclane, unsigned v) {
    return (unsigned)__builtin_amdgcn_ds_bpermute(srclane * 4, (int)v);
}

// K: fp8 swapped-A pair-frags; V: fp8 B pair-frags; W: bf16 frag-major (as R8/R9).
__global__ void prep_frags(const float* __restrict__ K, const float* __restrict__ V,
                           const float* __restrict__ W, uint8_t* __restrict__ ws) {
    const int bid = blockIdx.x, tid = threadIdx.x;
    const int lane = tid & 63, fb = tid >> 6, g = lane >> 4, nn = lane & 15;
    if (bid < BATCH * NKV) {
        const float* src = K + (size_t)bid * 32 * DIM;
        uint8_t* dst = ws + (size_t)bid * KT8;
#pragma unroll
        for (int p = 0; p < 2; ++p) {
            int pr = p * 4 + fb, t2 = pr >> 2, kk2 = pr & 3;
            const float* rp = src + (size_t)(t2 * 16 + nn) * DIM + kk2 * 64 + g * 8;
            float4 a  = *(const float4*)(rp);
            float4 a2 = *(const float4*)(rp + 4);
            float4 c  = *(const float4*)(rp + 32);
            float4 c2 = *(const float4*)(rp + 36);
            u32x4 u = {pk8x4(a.x, a.y, a.z, a.w), pk8x4(a2.x, a2.y, a2.z, a2.w),
                       pk8x4(c.x, c.y, c.z, c.w), pk8x4(c2.x, c2.y, c2.z, c2.w)};
            *(u32x4*)(dst + pr * 1024 + lane * 16) = u;
        }
    } else if (bid < 2 * BATCH * NKV) {
        const int id = bid - BATCH * NKV;
        const float* src = V + (size_t)id * 32 * DIM;
        uint8_t* dst = ws + VOFF + (size_t)id * KT8;
#pragma unroll
        for (int p = 0; p < 2; ++p) {
            int pr = p * 4 + fb;
            float v0[8], v1[8];
#pragma unroll
            for (int j = 0; j < 8; ++j) {
                v0[j] = src[(size_t)(g * 8 + j) * DIM + pr * 32 + nn];
                v1[j] = src[(size_t)(g * 8 + j) * DIM + pr * 32 + 16 + nn];
            }
            u32x4 u = {pk8x4(v0[0], v0[1], v0[2], v0[3]), pk8x4(v0[4], v0[5], v0[6], v0[7]),
                       pk8x4(v1[0], v1[1], v1[2], v1[3]), pk8x4(v1[4], v1[5], v1[6], v1[7])};
            *(u32x4*)(dst + pr * 1024 + lane * 16) = u;
        }
    } else {
        const int wt = bid - 2 * BATCH * NKV;
        const float* src = W + (size_t)wt * 32 * DIM;
        uint8_t* dst = ws + WOFF + (size_t)wt * WT;
#pragma unroll
        for (int p = 0; p < 4; ++p) {
            int d = p * 4 + fb;
            float v[8];
#pragma unroll
            for (int j = 0; j < 8; ++j)
                v[j] = src[(size_t)(g * 8 + j) * DIM + d * 16 + nn];
            u32x4 u = {pack2(v[0], v[1]), pack2(v[2], v[3]),
                       pack2(v[4], v[5]), pack2(v[6], v[7])};
            *(u32x4*)(dst + d * 1024 + lane * 16) = u;
        }
    }
}

// smem: cbuf f32[32][256] [0,32768) | cbn bf16[32][264] [32768,49664)
//       mws[4][32] [49664,50176) | lws [50176,50688) | lgb[32] [50688,50816)
#define SMEM_BYTES 50816

__launch_bounds__(256, 2)
__global__ void attn_main(const float* __restrict__ Q, const float* __restrict__ bias,
                          const uint8_t* __restrict__ ws, float* __restrict__ out) {
    __shared__ __align__(16) uint8_t smem[SMEM_BYTES];
    float* cbuf = (float*)smem;
    uint8_t* cbn = smem + 32768;
    float* mws = (float*)(smem + 49664);
    float* lws = (float*)(smem + 50176);
    float* lgb = (float*)(smem + 50688);

    const int tid = threadIdx.x;
    const int wid = tid >> 6, lane = tid & 63, g = lane >> 4, nn = lane & 15;
    const int b = blockIdx.x & 7, qg = blockIdx.x >> 3;   // batch -> XCD affinity
    const int q0 = qg * 32;

    {   // zero merge accumulator (ordered by the first __syncthreads)
        f32x4 z = {0.f, 0.f, 0.f, 0.f};
        float* p = cbuf + tid * 32;
#pragma unroll
        for (int i = 0; i < 8; ++i) *(f32x4*)(p + i * 4) = z;
    }

    // Q as fp8 B-frags for swapped QK, 2 q-subtiles (col=q=nn, k = t8*32 + g*8 + j)
    const float* qbase = Q + ((size_t)b * SEQ + q0 + nn) * DIM + g * 8;
    long long qp[2][8];
#pragma unroll
    for (int rt = 0; rt < 2; ++rt)
#pragma unroll
        for (int t8 = 0; t8 < 8; ++t8) {
            const float* rp = qbase + (size_t)rt * 16 * DIM + t8 * 32;
            float4 a = *(const float4*)(rp);
            float4 c = *(const float4*)(rp + 4);
            qp[rt][t8] = mk64(pk8x4(a.x, a.y, a.z, a.w), pk8x4(c.x, c.y, c.z, c.w));
        }

    f32x4 ctx[2][16];
#pragma unroll
    for (int rt = 0; rt < 2; ++rt)
#pragma unroll
        for (int d = 0; d < 16; ++d) ctx[rt][d] = (f32x4){0.f, 0.f, 0.f, 0.f};
    float m[2] = {-3e38f, -3e38f}, mc[2] = {0.f, 0.f}, l[2] = {0.f, 0.f};

    const uint8_t* kws = ws + ((size_t)b * NKV + wid * 16) * KT8 + lane * 16;
    const uint8_t* vws = ws + VOFF + ((size_t)b * NKV + wid * 16) * KT8 + lane * 16;

    for (int t = 0; t < 16; ++t) {
        const uint8_t* kf = kws + (size_t)t * KT8;
        const uint8_t* vf = vws + (size_t)t * KT8;
        // ALL tile loads at the top, as MFMA-ready 64-bit pairs (no operand marshalling)
        i64x2 kp[8];
#pragma unroll
        for (int i = 0; i < 8; ++i) kp[i] = *(const i64x2*)(kf + i * 1024);
        i64x2 vp[8];
#pragma unroll
        for (int i = 0; i < 8; ++i) vp[i] = *(const i64x2*)(vf + i * 1024);
        // ---- S^T = K Q for both q-subtiles (K frags shared) ----
        f32x4 s[2][2];
#pragma unroll
        for (int rt = 0; rt < 2; ++rt) { s[rt][0] = (f32x4){0.f,0.f,0.f,0.f}; s[rt][1] = s[rt][0]; }
        __builtin_amdgcn_s_setprio(1);
#pragma unroll
        for (int kk = 0; kk < 8; ++kk) {
            int i = kk >> 1, h = kk & 1;
            long long ka  = kp[i][h];
            long long kb2 = kp[4 + i][h];
#pragma unroll
            for (int rt = 0; rt < 2; ++rt) {
                s[rt][0] = __builtin_amdgcn_mfma_f32_16x16x32_fp8_fp8(ka,  qp[rt][kk], s[rt][0], 0, 0, 0);
                s[rt][1] = __builtin_amdgcn_mfma_f32_16x16x32_fp8_fp8(kb2, qp[rt][kk], s[rt][1], 0, 0, 0);
            }
        }
        __builtin_amdgcn_s_setprio(0);
        // ---- defer-max online softmax (per-lane scalar state, q = nn) ----
        float smax[2];
        int need = 0;
#pragma unroll
        for (int rt = 0; rt < 2; ++rt) {
            smax[rt] = fmaxf(fmaxf(fmaxf(s[rt][0][0], s[rt][0][1]), fmaxf(s[rt][0][2], s[rt][0][3])),
                             fmaxf(fmaxf(s[rt][1][0], s[rt][1][1]), fmaxf(s[rt][1][2], s[rt][1][3])));
            need |= (smax[rt] > m[rt] + THRRAW);
        }
        if (__any(need)) {                          // ~only at t=0 (cold path)
#pragma unroll
            for (int rt = 0; rt < 2; ++rt) {
                float v = smax[rt];
                v = fmaxf(v, __shfl_xor(v, 16));
                v = fmaxf(v, __shfl_xor(v, 32));
                float mn = fmaxf(m[rt], v);
                float sc0 = exp2_fast((m[rt] - mn) * C1);
                m[rt] = mn; mc[rt] = mn * C1; l[rt] *= sc0;
                float scr[4];
#pragma unroll
                for (int r = 0; r < 4; ++r)
                    scr[r] = __uint_as_float(bperm(4 * g + r, __float_as_uint(sc0)));
#pragma unroll
                for (int d = 0; d < 16; ++d)
#pragma unroll
                    for (int r = 0; r < 4; ++r) ctx[rt][d][r] *= scr[r];
            }
        }
        long long A[2];
#pragma unroll
        for (int rt = 0; rt < 2; ++rt) {
            float p0[4], p1[4];
#pragma unroll
            for (int r = 0; r < 4; ++r) {
                p0[r] = exp2_fast(__builtin_fmaf(s[rt][0][r], C1, -mc[rt]));   // <= 2^8 < 448
                p1[r] = exp2_fast(__builtin_fmaf(s[rt][1][r], C1, -mc[rt]));
                l[rt] += p0[r] + p1[r];
            }
            // P redistribution to PV A-layout via 2 permlane swaps (VALU, no LDS):
            // swap32: a=[kv0-7|kv16-23], b=[kv8-15|kv24-31]; swap16: a=kv[8g..], b=kv[8g+4..]
            unsigned pa  = pk8x4(p0[0], p0[1], p0[2], p0[3]);
            unsigned pb2 = pk8x4(p1[0], p1[1], p1[2], p1[3]);
            asm("v_permlane32_swap_b32 %0, %1" : "+v"(pa), "+v"(pb2));
            asm("v_permlane16_swap_b32 %0, %1" : "+v"(pa), "+v"(pb2));
            A[rt] = mk64(pa, pb2);
        }
        // ---- ctx += P V (V frags shared across subtiles; operands direct from vp) ----
        __builtin_amdgcn_s_setprio(1);
#pragma unroll
        for (int i = 0; i < 8; ++i) {
            long long v0 = vp[i][0], v1 = vp[i][1];
#pragma unroll
            for (int rt = 0; rt < 2; ++rt) {
                ctx[rt][2 * i]     = __builtin_amdgcn_mfma_f32_16x16x32_fp8_fp8(A[rt], v0, ctx[rt][2 * i], 0, 0, 0);
                ctx[rt][2 * i + 1] = __builtin_amdgcn_mfma_f32_16x16x32_fp8_fp8(A[rt], v1, ctx[rt][2 * i + 1], 0, 0, 0);
            }
        }
        __builtin_amdgcn_s_setprio(0);
    }

    // reduce l across the 4 lane-groups holding the same q
#pragma unroll
    for (int rt = 0; rt < 2; ++rt) {
        l[rt] += __shfl_xor(l[rt], 16);
        l[rt] += __shfl_xor(l[rt], 32);
    }

    if (lane < 16) {
#pragma unroll
        for (int rt = 0; rt < 2; ++rt) {
            mws[wid * 32 + rt * 16 + nn] = m[rt];
            lws[wid * 32 + rt * 16 + nn] = l[rt];
        }
    }
    __syncthreads();
    float sc[2][4];
#pragma unroll
    for (int rt = 0; rt < 2; ++rt)
#pragma unroll
        for (int r = 0; r < 4; ++r) {
            int row = rt * 16 + g * 4 + r;
            float m0 = mws[row], m1 = mws[32 + row], m2 = mws[64 + row], m3 = mws[96 + row];
            float mg = fmaxf(fmaxf(m0, m1), fmaxf(m2, m3));
            float lg = lws[row]      * exp2_fast((m0 - mg) * C1)
                     + lws[32 + row] * exp2_fast((m1 - mg) * C1)
                     + lws[64 + row] * exp2_fast((m2 - mg) * C1)
                     + lws[96 + row] * exp2_fast((m3 - mg) * C1);
            sc[rt][r] = exp2_fast((mws[wid * 32 + row] - mg) * C1);
            if (wid == 0 && nn == 0) lgb[row] = lg;
        }
    for (int w = 0; w < 4; ++w) {               // deterministic sequential merge
        if (wid == w) {
#pragma unroll
            for (int rt = 0; rt < 2; ++rt)
#pragma unroll
                for (int d = 0; d < 16; ++d)
#pragma unroll
                    for (int r = 0; r < 4; ++r) {
                        float* p = cbuf + (size_t)(rt * 16 + g * 4 + r) * 256 + d * 16 + nn;
                        *p += ctx[rt][d][r] * sc[rt][r];
                    }
        }
        __syncthreads();
    }
    {   // normalize + bf16 image cbn[32][264]
        int row = tid >> 3, c0 = (tid & 7) * 32;
        float il = 1.0f / lgb[row];
        const float* src = cbuf + (size_t)row * 256 + c0;
        uint8_t* dp = cbn + (size_t)row * 528 + c0 * 2;
#pragma unroll
        for (int i = 0; i < 4; ++i) {
            f32x4 a = *(const f32x4*)(src + i * 8);
            f32x4 c = *(const f32x4*)(src + i * 8 + 4);
            u32x4 u = {pack2(a[0] * il, a[1] * il), pack2(a[2] * il, a[3] * il),
                       pack2(c[0] * il, c[1] * il), pack2(c[2] * il, c[3] * il)};
            *(u32x4*)(dp + i * 16) = u;
        }
    }
    __syncthreads();

    // ---- epilogue: out = [ctxn, Q] @ W + b (bf16; Q reloaded) ----
    bf16x8 qe[2][8];
#pragma unroll
    for (int rt = 0; rt < 2; ++rt)
#pragma unroll
        for (int t8 = 0; t8 < 8; ++t8) {
            const float* rp = qbase + (size_t)rt * 16 * DIM + t8 * 32;
            float4 a = *(const float4*)(rp);
            float4 c = *(const float4*)(rp + 4);
            union { bf16x8 v; unsigned u[4]; } tmp;
            tmp.u[0] = pack2(a.x, a.y); tmp.u[1] = pack2(a.z, a.w);
            tmp.u[2] = pack2(c.x, c.y); tmp.u[3] = pack2(c.z, c.w);
            qe[rt][t8] = tmp.v;
        }
    f32x4 oacc[2][4];
#pragma unroll
    for (int rt = 0; rt < 2; ++rt)
#pragma unroll
        for (int dd = 0; dd < 4; ++dd) oacc[rt][dd] = (f32x4){0.f, 0.f, 0.f, 0.f};
    const uint8_t* wws = ws + WOFF + lane * 16;
    for (int wt = 0; wt < NWT; ++wt) {
        bf16x8 af[2];
#pragma unroll
        for (int rt = 0; rt < 2; ++rt) {
            if (wt < 8) af[rt] = *(const bf16x8*)(cbn + (size_t)(rt * 16 + nn) * 528 + wt * 64 + g * 16);
            else        af[rt] = qe[rt][wt - 8];
        }
#pragma unroll
        for (int dd = 0; dd < 4; ++dd) {
            bf16x8 wf = *(const bf16x8*)(wws + (size_t)(wt * 16 + wid * 4 + dd) * 1024);
#pragma unroll
            for (int rt = 0; rt < 2; ++rt)
                oacc[rt][dd] = __builtin_amdgcn_mfma_f32_16x16x32_bf16(af[rt], wf, oacc[rt][dd], 0, 0, 0);
        }
    }
#pragma unroll
    for (int rt = 0; rt < 2; ++rt) {
        float* obase = out + ((size_t)b * SEQ + q0 + rt * 16) * DIM + wid * 64;
#pragma unroll
        for (int dd = 0; dd < 4; ++dd) {
            float bv = bias[wid * 64 + dd * 16 + nn];
#pragma unroll
            for (int r = 0; r < 4; ++r)
                obase[(size_t)(g * 4 + r) * DIM + dd * 16 + nn] = oacc[rt][dd][r] + bv;
        }
    }
}

extern "C" void kernel_launch(void* const* d_in, const int* in_sizes, int n_in,
                              void* d_out, int out_size, void* d_ws, size_t ws_size,
                              hipStream_t stream) {
    const float* Q    = (const float*)d_in[0];
    const float* K    = (const float*)d_in[1];
    const float* V    = (const float*)d_in[2];
    const float* W    = (const float*)d_in[3];
    const float* bias = (const float*)d_in[4];
    float* out = (float*)d_out;
    uint8_t* ws = (uint8_t*)d_ws;
    prep_frags<<<2 * BATCH * NKV + NWT, 256, 0, stream>>>(K, V, W, ws);
    attn_main<<<BATCH * SEQ / 32, 256, 0, stream>>>(Q, bias, ws, out);
}